// Round 1
// baseline (600.522 us; speedup 1.0000x reference)
//
#include <hip/hip_runtime.h>
#include <hip/hip_cooperative_groups.h>

namespace cg = cooperative_groups;

#define NSEG 2048
#define EPS 1e-6f
#define TROWS 256              // rows per tile
#define TF4 (TROWS * 16)       // float4s per tile (4096)
#define GRID 1024              // 4 blocks/CU x 256 CUs -> co-resident for grid.sync
#define BLK 256

typedef float nfloat4 __attribute__((ext_vector_type(4)));  // native vec for nt store

// Monotonic float->uint key: preserves ordering so uint atomicMin/Max works.
__device__ __forceinline__ unsigned enc(float f) {
    unsigned u = __float_as_uint(f);
    return (u & 0x80000000u) ? ~u : (u | 0x80000000u);
}
__device__ __forceinline__ float dec(unsigned k) {
    unsigned u = (k & 0x80000000u) ? (k & 0x7FFFFFFFu) : ~k;
    return __uint_as_float(u);
}

__global__ void init_k(unsigned* __restrict__ mn_k, unsigned* __restrict__ mx_k) {
    int i = blockIdx.x * blockDim.x + threadIdx.x;
    if (i < NSEG) {
        mn_k[i] = 0xFFFFFFFFu;  // max key (encodes "+inf")
        mx_k[i] = 0u;           // min key
    }
}

__device__ __forceinline__ void wave_reduce(float& mn, float& mx) {
#pragma unroll
    for (int off = 32; off; off >>= 1) {
        mn = fminf(mn, __shfl_xor(mn, off));
        mx = fmaxf(mx, __shfl_xor(mx, off));
    }
}

// Single persistent cooperative kernel:
//   phase 1: grid-stride over 256-row tiles, segment min/max via uint atomics
//   grid.sync()
//   per-block: decode + reciprocal into a 16 KB LDS table (2048 x float2)
//   phase 2: SAME tile mapping (block re-reads what it just read -> L2/L3 hits),
//            normalize, nontemporal store (write-once, don't evict x from L3).
__global__ __launch_bounds__(BLK, 4) void fused(
        const float4* __restrict__ x4,
        const int* __restrict__ seg,
        unsigned* __restrict__ mn_k,
        unsigned* __restrict__ mx_k,
        nfloat4* __restrict__ out4,
        int nrows)
{
    __shared__ float2 sprm[NSEG];  // 16 KB: per-segment {min, 1/(max-min+eps)}
    const long n4 = (long)nrows * 16;
    const int nTiles = (nrows + TROWS - 1) / TROWS;
    const int t = threadIdx.x;

    // ---------------- phase 1: per-segment min/max ----------------
    for (int tile = blockIdx.x; tile < nTiles; tile += gridDim.x) {
        const long base = (long)tile * TF4;
        const int row0 = tile * TROWS;
        const int rlast = min(row0 + TROWS, nrows) - 1;
        const int sf = seg[row0];
        const int sl = seg[rlast];

        if (sf == sl) {
            // single-segment tile (~52%): private accumulate, 1 atomic pair/wave
            float lmin = INFINITY, lmax = -INFINITY;
#pragma unroll
            for (int i = 0; i < 16; ++i) {
                long f = base + (long)i * 256 + t;
                if (f < n4) {
                    float4 v = x4[f];
                    lmin = fminf(lmin, fminf(fminf(v.x, v.y), fminf(v.z, v.w)));
                    lmax = fmaxf(lmax, fmaxf(fmaxf(v.x, v.y), fmaxf(v.z, v.w)));
                }
            }
            wave_reduce(lmin, lmax);
            if ((t & 63) == 0) {
                atomicMin(&mn_k[sf], enc(lmin));
                atomicMax(&mx_k[sf], enc(lmax));
            }
        } else {
            // boundary tile: wave-segmented per iteration, still coalesced
            float amin = INFINITY, amax = -INFINITY;
            int as = -1;  // lane-0 accumulator segment
#pragma unroll
            for (int i = 0; i < 16; ++i) {
                long f = base + (long)i * 256 + t;
                bool valid = f < n4;
                float lmin = INFINITY, lmax = -INFINITY;
                int s = -1;
                if (valid) {
                    float4 v = x4[f];
                    lmin = fminf(fminf(v.x, v.y), fminf(v.z, v.w));
                    lmax = fmaxf(fmaxf(v.x, v.y), fmaxf(v.z, v.w));
                    s = seg[(int)(f >> 4)];
                }
                int s0 = __shfl(s, 0);  // lane0 has smallest f -> valid if any is
                if (__all(s == s0 || !valid)) {
                    if (s0 < 0) continue;  // whole wave past end
                    wave_reduce(lmin, lmax);
                    if ((t & 63) == 0) {
                        if (s0 != as) {
                            if (as >= 0) {
                                atomicMin(&mn_k[as], enc(amin));
                                atomicMax(&mx_k[as], enc(amax));
                            }
                            as = s0; amin = lmin; amax = lmax;
                        } else {
                            amin = fminf(amin, lmin);
                            amax = fmaxf(amax, lmax);
                        }
                    }
                } else {
                    // segment boundary inside this wave's rows (rare)
                    if (valid) {
                        atomicMin(&mn_k[s], enc(lmin));
                        atomicMax(&mx_k[s], enc(lmax));
                    }
                }
            }
            if ((t & 63) == 0 && as >= 0) {
                atomicMin(&mn_k[as], enc(amin));
                atomicMax(&mx_k[as], enc(amax));
            }
        }
    }

    cg::this_grid().sync();  // all segment min/max final + device-scope visible

    // ---------------- per-block LDS scale table ----------------
#pragma unroll
    for (int k = 0; k < NSEG / BLK; ++k) {
        int s = k * BLK + t;
        float mn = dec(mn_k[s]);
        float mx = dec(mx_k[s]);
        // exact-rounded divide, identical numerics to previous scalek
        sprm[s] = make_float2(mn, 1.0f / (mx - mn + EPS));
    }
    __syncthreads();

    // ---------------- phase 2: normalize (tile-affine re-read) ----------------
    for (int tile = blockIdx.x; tile < nTiles; tile += gridDim.x) {
        const long base = (long)tile * TF4;
#pragma unroll
        for (int i = 0; i < 16; ++i) {
            long f = base + (long)i * 256 + t;
            if (f < n4) {
                int row = (int)(f >> 4);
                int s = seg[row];      // 16 lanes/row share one dword -> L1 hit
                float2 p = sprm[s];    // LDS broadcast (same addr for 16 lanes)
                float4 v = x4[f];
                nfloat4 o;
                o.x = (v.x - p.x) * p.y;
                o.y = (v.y - p.x) * p.y;
                o.z = (v.z - p.x) * p.y;
                o.w = (v.w - p.x) * p.y;
                __builtin_nontemporal_store(o, &out4[f]);
            }
        }
    }
}

extern "C" void kernel_launch(void* const* d_in, const int* in_sizes, int n_in,
                              void* d_out, int out_size, void* d_ws, size_t ws_size,
                              hipStream_t stream) {
    const float4* x4 = (const float4*)d_in[0];
    const int* seg = (const int*)d_in[1];
    nfloat4* out4 = (nfloat4*)d_out;
    const int nrows = in_sizes[1];  // N = 1,000,000

    unsigned* mn_k = (unsigned*)d_ws;  // [NSEG]
    unsigned* mx_k = mn_k + NSEG;      // [NSEG]

    init_k<<<(NSEG + 255) / 256, 256, 0, stream>>>(mn_k, mx_k);

    void* args[] = {(void*)&x4, (void*)&seg, (void*)&mn_k, (void*)&mx_k,
                    (void*)&out4, (void*)&nrows};
    hipLaunchCooperativeKernel((const void*)fused, dim3(GRID), dim3(BLK),
                               args, 0, stream);
}

// Round 2
// 431.057 us; speedup vs baseline: 1.3931x; 1.3931x over previous
//
#include <hip/hip_runtime.h>

#define NSEG 2048
#define EPS 1e-6f
#define BLK 1024
#define RPT 10   // float4 per thread in register-resident path -> capacity 640 rows/segment
                 // (segment sizes ~ Binomial(1e6, 1/2048): mean 488, sd 22 -> 640 is ~7 sigma)

typedef float nfloat4 __attribute__((ext_vector_type(4)));  // native vec for nt store

// Build starts[0..NSEG]: starts[b] = first row index i with seg[i] >= b.
// seg is sorted, so every entry of starts is written exactly once (empty
// segments included: a boundary seg[i-1]=p -> seg[i]=s fills starts[p+1..s]=i).
__global__ void starts_k(const int* __restrict__ seg, int* __restrict__ starts, int n) {
    int i = blockIdx.x * blockDim.x + threadIdx.x;
    if (i >= n) return;
    int s = seg[i];
    int prev = (i == 0) ? -1 : seg[i - 1];
    for (int k = prev + 1; k <= s; ++k) starts[k] = i;
    if (i == n - 1) {
        for (int k = s + 1; k <= NSEG; ++k) starts[k] = n;
    }
}

__device__ __forceinline__ void wave_reduce(float& mn, float& mx) {
#pragma unroll
    for (int off = 32; off; off >>= 1) {
        mn = fminf(mn, __shfl_xor(mn, off));
        mx = fmaxf(mx, __shfl_xor(mx, off));
    }
}

__device__ __forceinline__ void min4max4(const float4& v, float& mn, float& mx) {
    mn = fminf(mn, fminf(fminf(v.x, v.y), fminf(v.z, v.w)));
    mx = fmaxf(mx, fmaxf(fmaxf(v.x, v.y), fmaxf(v.z, v.w)));
}

// One block per segment. Segment data (avg ~122 KB) lives in REGISTERS:
// load once (RPT independent loads in flight -> HBM latency hidden by ILP),
// block-reduce min/max, normalize from registers, nontemporal store.
// Single global read + single global write; no atomics, no grid sync.
__global__ __launch_bounds__(BLK, 4) void norm_seg(const float4* __restrict__ x4,
                                                   const int* __restrict__ starts,
                                                   nfloat4* __restrict__ out4) {
    const int b = blockIdx.x;
    const long f0 = (long)starts[b] * 16;   // rows are 16 float4 each (D=64)
    const int n = (int)((long)starts[b + 1] * 16 - f0);  // float4 count of segment
    if (n <= 0) return;                     // empty segment
    const int t = threadIdx.x;
    __shared__ float2 red[BLK / 64];

    float lmin = INFINITY, lmax = -INFINITY;

    if (n <= BLK * RPT) {
        // ---------- register-resident path (essentially always) ----------
        float4 v[RPT];
#pragma unroll
        for (int i = 0; i < RPT; ++i) {      // batch loads: all independent, issued back-to-back
            int idx = i * BLK + t;
            if (idx < n) v[i] = x4[f0 + idx];
        }
#pragma unroll
        for (int i = 0; i < RPT; ++i) {
            int idx = i * BLK + t;
            if (idx < n) min4max4(v[i], lmin, lmax);
        }
        wave_reduce(lmin, lmax);
        if ((t & 63) == 0) red[t >> 6] = make_float2(lmin, lmax);
        __syncthreads();
        float mn = INFINITY, mx = -INFINITY;
#pragma unroll
        for (int w = 0; w < BLK / 64; ++w) {  // redundant final reduce: 16 LDS broadcasts
            mn = fminf(mn, red[w].x);
            mx = fmaxf(mx, red[w].y);
        }
        const float sc = 1.0f / (mx - mn + EPS);  // same numerics as passing kernel
#pragma unroll
        for (int i = 0; i < RPT; ++i) {
            int idx = i * BLK + t;
            if (idx < n) {
                nfloat4 o;
                o.x = (v[i].x - mn) * sc;
                o.y = (v[i].y - mn) * sc;
                o.z = (v[i].z - mn) * sc;
                o.w = (v[i].w - mn) * sc;
                __builtin_nontemporal_store(o, &out4[f0 + idx]);
            }
        }
    } else {
        // ---------- fallback: oversized segment, chunked two-pass ----------
        for (int base = 0; base < n; base += BLK * RPT) {
            float4 v[RPT];
#pragma unroll
            for (int i = 0; i < RPT; ++i) {
                int idx = base + i * BLK + t;
                if (idx < n) v[i] = x4[f0 + idx];
            }
#pragma unroll
            for (int i = 0; i < RPT; ++i) {
                int idx = base + i * BLK + t;
                if (idx < n) min4max4(v[i], lmin, lmax);
            }
        }
        wave_reduce(lmin, lmax);
        if ((t & 63) == 0) red[t >> 6] = make_float2(lmin, lmax);
        __syncthreads();
        float mn = INFINITY, mx = -INFINITY;
#pragma unroll
        for (int w = 0; w < BLK / 64; ++w) {
            mn = fminf(mn, red[w].x);
            mx = fmaxf(mx, red[w].y);
        }
        const float sc = 1.0f / (mx - mn + EPS);
        for (int base = 0; base < n; base += BLK * RPT) {  // re-read (L2-hot for sane sizes)
#pragma unroll
            for (int i = 0; i < RPT; ++i) {
                int idx = base + i * BLK + t;
                if (idx < n) {
                    float4 v = x4[f0 + idx];
                    nfloat4 o;
                    o.x = (v.x - mn) * sc;
                    o.y = (v.y - mn) * sc;
                    o.z = (v.z - mn) * sc;
                    o.w = (v.w - mn) * sc;
                    __builtin_nontemporal_store(o, &out4[f0 + idx]);
                }
            }
        }
    }
}

extern "C" void kernel_launch(void* const* d_in, const int* in_sizes, int n_in,
                              void* d_out, int out_size, void* d_ws, size_t ws_size,
                              hipStream_t stream) {
    const float4* x4 = (const float4*)d_in[0];
    const int* seg = (const int*)d_in[1];
    nfloat4* out4 = (nfloat4*)d_out;
    const int nrows = in_sizes[1];  // N = 1,000,000 (element count of seg)

    int* starts = (int*)d_ws;  // [NSEG + 1], fully rewritten every call

    starts_k<<<(nrows + 255) / 256, 256, 0, stream>>>(seg, starts, nrows);
    norm_seg<<<NSEG, BLK, 0, stream>>>(x4, starts, out4);
}